// Round 5
// baseline (1840.185 us; speedup 1.0000x reference)
//
#include <hip/hip_runtime.h>
#include <math.h>

#define N_PTS 6000
#define DIM   1024
#define KSEL  300
#define GG    16
#define DGR   64
#define WSTR  6016   // padded row stride for logits W (6000 -> 6016)
#define XSTR  3072   // X = [hi|mid|lo] bf16 split, row stride

typedef short bf16x8 __attribute__((ext_vector_type(8)));
typedef float floatx4 __attribute__((ext_vector_type(4)));

__device__ __forceinline__ unsigned short f2bf(float x) {
    unsigned u = __float_as_uint(x);
    unsigned r = u + 0x7FFFu + ((u >> 16) & 1u);   // RNE
    return (unsigned short)(r >> 16);
}
__device__ __forceinline__ float bf2f(unsigned short h) {
    return __uint_as_float(((unsigned)h) << 16);
}

__device__ __forceinline__ void async_copy16(const void* gsrc, void* ldst) {
    __builtin_amdgcn_global_load_lds(
        (const __attribute__((address_space(1))) void*)gsrc,
        (__attribute__((address_space(3))) void*)ldst,
        16, 0, 0);
}

// ---------------------------------------------------------------------------
// MFMA bf16 GEMM, NT: C[i][j] = scale * sum_k A[i,k]*B[j,k] (+bias[j])
// 128x128 tile, BK=32, 256 threads (4 waves, each 64x64 = 4x4 16x16 tiles).
// GRAM: A=B=X=[hi|mid|lo] (lda 3072), logical K=6144, per-1024-chunk remap
//       realizing hi.hi + hi.mid + mid.hi + mid.mid + hi.lo + lo.hi
//       (== x.y to ~fp32 accuracy); triangular grid (bi<=bj),
//       1/cdist epilogue + mirrored store.
// OBF16: store output as bf16 (for q, kk feeding the aff MFMA).
// ---------------------------------------------------------------------------
template<bool GRAM, bool OBF16>
__global__ __launch_bounds__(256)
void mfma_gemm(const void* Av, long lda, long az,
               const void* Bv, long ldb, long bz,
               void* Cv, long ldc, long cz,
               int M, int N, int Kd,
               const float* __restrict__ bias, long biasz,
               float scale, const float* __restrict__ sqn, int nbm)
{
    __shared__ unsigned short As[128 * 32];
    __shared__ unsigned short Bs[128 * 32];
    const int t = threadIdx.x;
    const int w = t >> 6, l = t & 63;
    const int wr = w >> 1, wc = w & 1;

    int row0, col0, bi = 0, bj = 0;
    if (GRAM) {
        int tt = blockIdx.x, rem = nbm;
        while (tt >= rem) { tt -= rem; bi++; rem--; }
        bj = bi + tt;
        row0 = bi * 128; col0 = bj * 128;
    } else {
        row0 = blockIdx.y * 128; col0 = blockIdx.x * 128;
    }
    const int z = blockIdx.z;
    const unsigned short* Ab = (const unsigned short*)Av + (long)z * az;
    const unsigned short* Bb = (const unsigned short*)Bv + (long)z * bz;

    floatx4 acc[4][4];
#pragma unroll
    for (int i = 0; i < 4; i++)
#pragma unroll
        for (int j = 0; j < 4; j++) acc[i][j] = (floatx4){0.f, 0.f, 0.f, 0.f};

    for (int k0 = 0; k0 < Kd; k0 += 32) {
        long offA, offB;
        if (GRAM) {
            // chunk kb: (A part, B part) from
            // {hi.hi, hi.mid, mid.hi, mid.mid, hi.lo, lo.hi}; parts hi=0,mid=1,lo=2
            const int kb = k0 >> 10;
            const int pa[6] = {0, 0, 1, 1, 0, 2};
            const int pb[6] = {0, 1, 0, 1, 2, 0};
            offA = (k0 & 1023) + pa[kb] * 1024;
            offB = (k0 & 1023) + pb[kb] * 1024;
        } else { offA = k0; offB = k0; }

#pragma unroll
        for (int i = 0; i < 2; i++) {
            int rowa = row0 + (w * 2 + i) * 16 + (l >> 2);
            rowa = rowa < M ? rowa : M - 1;
            const unsigned short* g = Ab + (long)rowa * lda + offA + (l & 3) * 8;
            async_copy16(g, (void*)(As + ((w * 2 + i) * 16) * 32));
        }
#pragma unroll
        for (int i = 0; i < 2; i++) {
            int rowb = col0 + (w * 2 + i) * 16 + (l >> 2);
            rowb = rowb < N ? rowb : N - 1;
            const unsigned short* g = Bb + (long)rowb * ldb + offB + (l & 3) * 8;
            async_copy16(g, (void*)(Bs + ((w * 2 + i) * 16) * 32));
        }
        __syncthreads();

        bf16x8 af[4], bfr[4];
#pragma unroll
        for (int ti = 0; ti < 4; ti++)
            af[ti] = *(const bf16x8*)(As + (wr * 64 + ti * 16 + (l & 15)) * 32 + (l >> 4) * 8);
#pragma unroll
        for (int tj = 0; tj < 4; tj++)
            bfr[tj] = *(const bf16x8*)(Bs + (wc * 64 + tj * 16 + (l & 15)) * 32 + (l >> 4) * 8);
#pragma unroll
        for (int ti = 0; ti < 4; ti++)
#pragma unroll
            for (int tj = 0; tj < 4; tj++)
                acc[ti][tj] = __builtin_amdgcn_mfma_f32_16x16x32_bf16(
                    af[ti], bfr[tj], acc[ti][tj], 0, 0, 0);
        __syncthreads();
    }

    float* Cf = (float*)Cv + (long)z * cz;
    unsigned short* Cb = (unsigned short*)Cv + (long)z * cz;
    const float* bias_p = bias ? bias + (long)z * biasz : nullptr;
#pragma unroll
    for (int ti = 0; ti < 4; ti++) {
#pragma unroll
        for (int tj = 0; tj < 4; tj++) {
            const int c = col0 + wc * 64 + tj * 16 + (l & 15);
            const int rb = row0 + wr * 64 + ti * 16 + (l >> 4) * 4;
            if (GRAM) {
                float rec4[4];
#pragma unroll
                for (int reg = 0; reg < 4; reg++) {
                    int r = rb + reg;
                    if (r >= M || c >= N) { rec4[reg] = 0.f; continue; }
                    if (r == c) { rec4[reg] = INFINITY; }
                    else {
                        float sq = sqn[r] + sqn[c] - 2.f * acc[ti][tj][reg];
                        rec4[reg] = 1.0f / sqrtf(fmaxf(sq, 0.f));
                    }
                    Cf[(long)r * ldc + c] = rec4[reg];
                }
                if (bi != bj && c < N && rb + 3 < M) {  // mirrored float4 store
                    *(float4*)(Cf + (long)c * ldc + rb) =
                        make_float4(rec4[0], rec4[1], rec4[2], rec4[3]);
                }
            } else {
#pragma unroll
                for (int reg = 0; reg < 4; reg++) {
                    int r = rb + reg;
                    if (r >= M || c >= N) continue;
                    float v = acc[ti][tj][reg] * scale;
                    if (bias_p) v += bias_p[c];
                    if (OBF16) Cb[(long)r * ldc + c] = f2bf(v);
                    else       Cf[(long)r * ldc + c] = v;
                }
            }
        }
    }
}

// ---------------------------------------------------------------------------
// fp32 SGEMM kept for the small Wv projection only.
// ---------------------------------------------------------------------------
#define BM 128
#define BN 128
#define BKK 8
#define TM 8
#define TN 8

template<bool TRANSB>
__global__ __launch_bounds__(256)
void sgemm_kernel(const float* __restrict__ A, long lda, long az,
                  const float* __restrict__ B, long ldb, long bz,
                  float* __restrict__ C, long ldc, long cz,
                  int M, int N, int Kd,
                  const float* __restrict__ bias, long biasz, float scale)
{
    __shared__ float As[BKK][BM];
    __shared__ float Bs[BKK][BN];
    const int t = threadIdx.x;
    const int z = blockIdx.z;
    A += (long)z * az; B += (long)z * bz; C += (long)z * cz;
    const float* bias_p = bias ? (bias + (long)z * biasz) : nullptr;
    const int row0 = blockIdx.y * BM;
    const int col0 = blockIdx.x * BN;
    const int tx = t & 15, ty = t >> 4;

    float acc[TM][TN];
#pragma unroll
    for (int i = 0; i < TM; i++)
#pragma unroll
        for (int j = 0; j < TN; j++) acc[i][j] = 0.f;

    const int lrow = t >> 1;
    const int lcol = (t & 1) * 4;

    for (int k0 = 0; k0 < Kd; k0 += BKK) {
        {
            int r = row0 + lrow; r = (r < M) ? r : (M - 1);
            float4 v = *(const float4*)(A + (long)r * lda + (k0 + lcol));
            As[lcol + 0][lrow] = v.x; As[lcol + 1][lrow] = v.y;
            As[lcol + 2][lrow] = v.z; As[lcol + 3][lrow] = v.w;
        }
        {
            int r = col0 + lrow; r = (r < N) ? r : (N - 1);
            float4 v = *(const float4*)(B + (long)r * ldb + (k0 + lcol));
            Bs[lcol + 0][lrow] = v.x; Bs[lcol + 1][lrow] = v.y;
            Bs[lcol + 2][lrow] = v.z; Bs[lcol + 3][lrow] = v.w;
        }
        __syncthreads();
#pragma unroll
        for (int kk = 0; kk < BKK; kk++) {
            float a[TM], b[TN];
#pragma unroll
            for (int i = 0; i < TM; i++) a[i] = As[kk][ty * TM + i];
#pragma unroll
            for (int j = 0; j < TN; j++) b[j] = Bs[kk][tx * TN + j];
#pragma unroll
            for (int i = 0; i < TM; i++)
#pragma unroll
                for (int j = 0; j < TN; j++)
                    acc[i][j] = fmaf(a[i], b[j], acc[i][j]);
        }
        __syncthreads();
    }
#pragma unroll
    for (int i = 0; i < TM; i++) {
        int r = row0 + ty * TM + i;
        if (r >= M) continue;
#pragma unroll
        for (int j = 0; j < TN; j++) {
            int c = col0 + tx * TN + j;
            if (c >= N) continue;
            float v = acc[i][j] * scale;
            if (bias_p) v += bias_p[c];
            C[(long)r * ldc + c] = v;
        }
    }
}

// ---------------------------------------------------------------------------
__global__ __launch_bounds__(256)
void sqn_kernel(const float* __restrict__ feat, float* __restrict__ sqn)
{
    const int r = blockIdx.x, t = threadIdx.x;
    float4 v = *(const float4*)(feat + (long)r * DIM + t * 4);
    float s = v.x * v.x + v.y * v.y + v.z * v.z + v.w * v.w;
#pragma unroll
    for (int o = 32; o > 0; o >>= 1) s += __shfl_down(s, o);
    __shared__ float sr[4];
    if ((t & 63) == 0) sr[t >> 6] = s;
    __syncthreads();
    if (t == 0) sqn[r] = sr[0] + sr[1] + sr[2] + sr[3];
}

// X = [hi|mid|lo] bf16 3-way split of feat, row stride 3072.
__global__ __launch_bounds__(256)
void pack3_kernel(const float* __restrict__ feat, unsigned short* __restrict__ X)
{
    const int r = blockIdx.x, t = threadIdx.x;
    float4 v = *(const float4*)(feat + (long)r * DIM + t * 4);
    ushort4 hi, mid, lo;
    float rx, ry, rz, rw;
    hi.x = f2bf(v.x); rx = v.x - bf2f(hi.x);
    hi.y = f2bf(v.y); ry = v.y - bf2f(hi.y);
    hi.z = f2bf(v.z); rz = v.z - bf2f(hi.z);
    hi.w = f2bf(v.w); rw = v.w - bf2f(hi.w);
    mid.x = f2bf(rx); rx -= bf2f(mid.x);
    mid.y = f2bf(ry); ry -= bf2f(mid.y);
    mid.z = f2bf(rz); rz -= bf2f(mid.z);
    mid.w = f2bf(rw); rw -= bf2f(mid.w);
    lo.x = f2bf(rx); lo.y = f2bf(ry); lo.z = f2bf(rz); lo.w = f2bf(rw);
    *(ushort4*)(X + (long)r * XSTR + t * 4) = hi;
    *(ushort4*)(X + (long)r * XSTR + 1024 + t * 4) = mid;
    *(ushort4*)(X + (long)r * XSTR + 2048 + t * 4) = lo;
}

__global__ __launch_bounds__(256)
void wconv_kernel(const float* __restrict__ src, unsigned short* __restrict__ dst)
{
    const long i = ((long)blockIdx.x * 256 + threadIdx.x) * 4;
    float4 v = *(const float4*)(src + i);
    ushort4 o;
    o.x = f2bf(v.x); o.y = f2bf(v.y); o.z = f2bf(v.z); o.w = f2bf(v.w);
    *(ushort4*)(dst + i) = o;
}

// featT[d][r] = bf16(feat[r][d]), 1024 x 6016 (cols 6000..6015 zero)
__global__ __launch_bounds__(256)
void transpose_kernel(const float* __restrict__ feat, unsigned short* __restrict__ featT)
{
    __shared__ unsigned short tile[32][33];
    const int bx = blockIdx.x;   // d-block 0..31
    const int by = blockIdx.y;   // r-block 0..187
    const int t = threadIdx.x;
    const int lr = t >> 3;
    const int lc = (t & 7) * 4;
    const int r = by * 32 + lr;
    if (r < N_PTS) {
        float4 v = *(const float4*)(feat + (long)r * DIM + bx * 32 + lc);
        tile[lr][lc + 0] = f2bf(v.x); tile[lr][lc + 1] = f2bf(v.y);
        tile[lr][lc + 2] = f2bf(v.z); tile[lr][lc + 3] = f2bf(v.w);
    } else {
        tile[lr][lc + 0] = 0; tile[lr][lc + 1] = 0;
        tile[lr][lc + 2] = 0; tile[lr][lc + 3] = 0;
    }
    __syncthreads();
    const int orow = bx * 32 + lr;
    ushort4 o;
    o.x = tile[lc + 0][lr]; o.y = tile[lc + 1][lr];
    o.z = tile[lc + 2][lr]; o.w = tile[lc + 3][lr];
    *(ushort4*)(featT + (long)orow * WSTR + by * 32 + lc) = o;
}

// ---------------------------------------------------------------------------
// Greedy FPS, latency-optimized: 512 threads x 12 elements, ONE barrier per
// iteration. Butterfly shfl_xor -> all lanes hold wave min; 8 wave-mins in
// double-buffered LDS; after the barrier every thread reduces the 8 keys in
// registers (broadcast LDS reads). Same u64 (valbits<<32|idx) keys and same
// per-element add order as before => bit-identical selections.
// ---------------------------------------------------------------------------
#define FPS_T 512
#define FPS_E 12

__global__ __launch_bounds__(512)
void fps_kernel(const float* __restrict__ Drec, int* __restrict__ idxout)
{
    const int t = threadIdx.x;
    const int wv = t >> 6;
    float ds[FPS_E];
#pragma unroll
    for (int j = 0; j < FPS_E; j++) {
        int n = t + j * FPS_T;
        ds[j] = (n < N_PTS) ? Drec[n] : INFINITY;
    }
    __shared__ __align__(16) unsigned long long red[2][8];
    if (t == 0) idxout[0] = 0;

    for (int it = 1; it < KSEL; it++) {
        const int buf = it & 1;
        // local argmin (j ascending => lowest n wins ties)
        unsigned long long key = ~0ull;
#pragma unroll
        for (int j = 0; j < FPS_E; j++) {
            unsigned long long kj =
                ((unsigned long long)__float_as_uint(ds[j]) << 32)
                | (unsigned)(t + j * FPS_T);
            key = (kj < key) ? kj : key;
        }
        // wave butterfly: all 64 lanes end with the wave min
#pragma unroll
        for (int o = 1; o < 64; o <<= 1) {
            unsigned long long other = __shfl_xor(key, o);
            key = (other < key) ? other : key;
        }
        if ((t & 63) == 0) red[buf][wv] = key;
        __syncthreads();
        // every thread finishes the argmin in registers (broadcast reads)
        unsigned long long best = red[buf][0];
#pragma unroll
        for (int i = 1; i < 8; i++) {
            unsigned long long other = red[buf][i];
            best = (other < best) ? other : best;
        }
        const int sel = (int)(unsigned)best;
        if (t == 0) idxout[it] = sel;
        const float* row = Drec + (long)sel * N_PTS;
#pragma unroll
        for (int j = 0; j < FPS_E; j++) {
            int n = t + j * FPS_T;
            if (n < N_PTS) ds[j] += row[n];
        }
    }
}

__global__ __launch_bounds__(256)
void gatherb_kernel(const unsigned short* __restrict__ X, const int* __restrict__ idx,
                    unsigned short* __restrict__ roi)
{
    const int k = blockIdx.x, t = threadIdx.x;
    const unsigned short* src = X + (long)idx[k] * XSTR;
    *(ushort4*)(roi + (long)k * DIM + t * 4) = *(const ushort4*)(src + t * 4);
}

// ---------------------------------------------------------------------------
// Fused gate + softmax: one block per (k,g) row of W.
//   logit[n] = aff[n] + log(relu(bg[g] + Wg[g].emb(k,n)) + 1e-6)
//   p[n] = softmax_n(logit); row overwritten IN PLACE as bf16 (stride WSTR*2
//   shorts), cols 6000..6015 zeroed. Native __sinf/__cosf/__logf/__expf:
//   errors only significant where gate ~ 0+ i.e. softmax weight is ~1e3x
//   suppressed -> output impact ~1e-6.
// ---------------------------------------------------------------------------
__global__ __launch_bounds__(256)
void gatesoftmax_kernel(const float* __restrict__ bboxes,
                        const int* __restrict__ idx,
                        const float* __restrict__ Wg,
                        const float* __restrict__ bgp,
                        float* __restrict__ W)
{
    __shared__ float lg[WSTR];      // 24 KB: logits, then exp values
    __shared__ float swg[64];
    __shared__ float sred[4];
    __shared__ float sbb[4];
    __shared__ float sMS;
    const int t = threadIdx.x;
    const int row = blockIdx.x;     // k*GG + g
    const int k = row >> 4, g = row & 15;
    float* rowp = W + (long)row * WSTR;

    if (t < 64) swg[t] = Wg[g * 64 + t];
    if (t < 4)  sbb[t] = bboxes[(long)idx[k] * 4 + t];
    __syncthreads();

    const float x1 = sbb[0], y1 = sbb[1], x2 = sbb[2], y2 = sbb[3];
    const float w  = x2 - x1 + 1.f, h = y2 - y1 + 1.f;
    const float cx = 0.5f * (x1 + x2), cy = 0.5f * (y1 + y2);
    const float bg_g = bgp[g];
    // 100 / dmat[f]
    const float rdm[8] = { 100.0f, 42.169650342858226f, 17.782794100389228f,
                           7.498942093324559f, 3.1622776601683795f,
                           1.333521432163324f, 0.5623413251903491f,
                           0.23713737056616552f };

    float m = -INFINITY;
    for (int n = t; n < N_PTS; n += 256) {
        const float aff = rowp[n];
        float4 rb = *(const float4*)(bboxes + (long)n * 4);
        const float wr = rb.z - rb.x + 1.f, hr = rb.w - rb.y + 1.f;
        const float cxr = 0.5f * (rb.x + rb.z), cyr = 0.5f * (rb.y + rb.w);
        float pos[4];
        pos[0] = __logf(fabsf((cx - cxr) / w) + 1e-3f);
        pos[1] = __logf(fabsf((cy - cyr) / h) + 1e-3f);
        pos[2] = __logf(w / wr);
        pos[3] = __logf(h / hr);
        float gate = bg_g;
#pragma unroll
        for (int p = 0; p < 4; p++) {
#pragma unroll
            for (int f = 0; f < 8; f++) {
                const float arg = pos[p] * rdm[f];
                gate += swg[p * 16 + f] * __sinf(arg)
                      + swg[p * 16 + f + 8] * __cosf(arg);
            }
        }
        const float logit = aff + __logf(fmaxf(gate, 0.f) + 1e-6f);
        lg[n] = logit;
        m = fmaxf(m, logit);
    }
#pragma unroll
    for (int o = 32; o > 0; o >>= 1) m = fmaxf(m, __shfl_down(m, o));
    if ((t & 63) == 0) sred[t >> 6] = m;
    __syncthreads();
    if (t == 0) sMS = fmaxf(fmaxf(sred[0], sred[1]), fmaxf(sred[2], sred[3]));
    __syncthreads();
    m = sMS;
    __syncthreads();

    float s = 0.f;
    for (int n = t; n < N_PTS; n += 256) {
        const float e = __expf(lg[n] - m);
        lg[n] = e;
        s += e;
    }
#pragma unroll
    for (int o = 32; o > 0; o >>= 1) s += __shfl_down(s, o);
    if ((t & 63) == 0) sred[t >> 6] = s;
    __syncthreads();
    if (t == 0) sMS = sred[0] + sred[1] + sred[2] + sred[3];
    __syncthreads();
    const float inv = 1.0f / sMS;
    __syncthreads();

    // overwrite row in place as bf16 (this block owns the whole row)
    unsigned short* orow = (unsigned short*)rowp;
    for (int n = t; n < WSTR; n += 256)
        orow[n] = (n < N_PTS) ? f2bf(lg[n] * inv) : (unsigned short)0;
}

// ---------------------------------------------------------------------------
extern "C" void kernel_launch(void* const* d_in, const int* in_sizes, int n_in,
                              void* d_out, int out_size, void* d_ws, size_t ws_size,
                              hipStream_t stream)
{
    const float* feat   = (const float*)d_in[0];
    const float* bboxes = (const float*)d_in[1];
    const float* Wq     = (const float*)d_in[2];
    const float* bq     = (const float*)d_in[3];
    const float* Wk     = (const float*)d_in[4];
    const float* bk     = (const float*)d_in[5];
    const float* Wg     = (const float*)d_in[6];
    const float* bg     = (const float*)d_in[7];
    const float* Wv     = (const float*)d_in[8];
    const float* bv     = (const float*)d_in[9];
    float* out = (float*)d_out;
    float* ws  = (float*)d_ws;

    // ws layout (float offsets), peak ~185.1 MB (same as R4):
    //  [0 .. 36,000,000)  drec 6000x6000. Dead after FPS; then reused:
    //      W     [0, 28,876,800)            4800 x 6016 logits (fp32 -> bf16 in place)
    //      kk_b  [28,900,000, 31,972,000)   6000x1024 bf16
    //      q_b   [31,972,000, 32,125,600)   300x1024 bf16
    //      roi_b [32,125,600, 32,279,200)   300x1024 bf16
    //      featT [32,300,000, 35,380,192)   1024x6016 bf16 (written post-FPS)
    //  [36,000,000 .. 45,216,000)  X=[hi|mid|lo] 6000x3072 bf16
    //      -> outt fp32 4800x1024 reuses [36,000,000, 40,915,200) after kk/gather
    //  [45,216,000 .. 45,740,288)  Wq_b
    //  [45,740,288 .. 46,264,576)  Wk_b
    //  [46,264,576 .. 46,270,576)  sqn
    //  [46,270,576 .. )            idx (300 ints)
    float* drec = ws;
    float* W    = ws;
    unsigned short* kk_b  = (unsigned short*)(ws + 28900000);
    unsigned short* q_b   = (unsigned short*)(ws + 31972000);
    unsigned short* roi_b = (unsigned short*)(ws + 32125600);
    unsigned short* featT = (unsigned short*)(ws + 32300000);
    unsigned short* X     = (unsigned short*)(ws + 36000000);
    float* outt           = ws + 36000000;
    unsigned short* Wq_b  = (unsigned short*)(ws + 45216000);
    unsigned short* Wk_b  = (unsigned short*)(ws + 45740288);
    float* sqnbuf         = ws + 46264576;
    int*   idxbuf         = (int*)(ws + 46270576);
    if (ws_size < (size_t)185100000) return;

    sqn_kernel<<<N_PTS, 256, 0, stream>>>(feat, sqnbuf);
    pack3_kernel<<<N_PTS, 256, 0, stream>>>(feat, X);
    wconv_kernel<<<1024, 256, 0, stream>>>(Wq, Wq_b);
    wconv_kernel<<<1024, 256, 0, stream>>>(Wk, Wk_b);

    // Gram: 3-way split bf16, 6 cross terms (logical K=6144), triangular grid
    mfma_gemm<true, false><<<1128, 256, 0, stream>>>(
        X, XSTR, 0, X, XSTR, 0, drec, N_PTS, 0,
        N_PTS, N_PTS, 6144, nullptr, 0, 1.f, sqnbuf, 47);

    fps_kernel<<<1, FPS_T, 0, stream>>>(drec, idxbuf);

    // featT goes into dead drec space -> must run after FPS
    transpose_kernel<<<dim3(32, 188), 256, 0, stream>>>(feat, featT);
    gatherb_kernel<<<KSEL, 256, 0, stream>>>(X, idxbuf, roi_b);

    // q = roi @ Wq^T + bq  (bf16 out)
    mfma_gemm<false, true><<<dim3(8, 3, 1), 256, 0, stream>>>(
        roi_b, 1024, 0, Wq_b, 1024, 0, q_b, 1024, 0,
        KSEL, DIM, DIM, bq, 0, 1.f, nullptr, 0);
    // kk = feat @ Wk^T + bk  (bf16 out; A = hi part of X, lda XSTR)
    mfma_gemm<false, true><<<dim3(8, 47, 1), 256, 0, stream>>>(
        X, XSTR, 0, Wk_b, 1024, 0, kk_b, 1024, 0,
        N_PTS, DIM, DIM, bk, 0, 1.f, nullptr, 0);

    // aff = (q . kk^T)/8 per group -> W fp32  (batched z=16, K=64)
    mfma_gemm<false, false><<<dim3(47, 3, GG), 256, 0, stream>>>(
        q_b, 1024, 64, kk_b, 1024, 64, W, (long)GG * WSTR, WSTR,
        KSEL, N_PTS, 64, nullptr, 0, 0.125f, nullptr, 0);

    // fused gate + softmax; W rows become bf16 probs in place (stride 2*WSTR shorts)
    gatesoftmax_kernel<<<KSEL * GG, 256, 0, stream>>>(bboxes, idxbuf, Wg, bg, W);

    // out_t = P @ feat  (A = bf16 probs in place, lda 2*WSTR shorts; B = featT)
    mfma_gemm<false, false><<<dim3(8, 38, 1), 256, 0, stream>>>(
        (unsigned short*)W, 2 * WSTR, 0, featT, WSTR, 0, outt, DIM, 0,
        KSEL * GG, DIM, WSTR, nullptr, 0, 1.f, nullptr, 0);

    // out = out_t . Wv + bv (fp32, small)
    sgemm_kernel<true><<<dim3(1, 3, GG), 256, 0, stream>>>(
        outt, (long)GG * DIM, DIM, Wv, DIM, (long)DGR * DIM, out, DIM, DGR,
        KSEL, DGR, DIM, bv, DGR, 1.f);
}

// Round 6
// 1669.360 us; speedup vs baseline: 1.1023x; 1.1023x over previous
//
#include <hip/hip_runtime.h>
#include <math.h>

#define N_PTS 6000
#define DIM   1024
#define KSEL  300
#define GG    16
#define DGR   64
#define WSTR  6016   // padded row stride for logits W (6000 -> 6016)
#define XSTR  3072   // X = [hi|mid|lo] bf16 split, row stride

typedef short bf16x8 __attribute__((ext_vector_type(8)));
typedef float floatx4 __attribute__((ext_vector_type(4)));

__device__ __forceinline__ unsigned short f2bf(float x) {
    unsigned u = __float_as_uint(x);
    unsigned r = u + 0x7FFFu + ((u >> 16) & 1u);   // RNE
    return (unsigned short)(r >> 16);
}
__device__ __forceinline__ float bf2f(unsigned short h) {
    return __uint_as_float(((unsigned)h) << 16);
}

__device__ __forceinline__ void async_copy16(const void* gsrc, void* ldst) {
    __builtin_amdgcn_global_load_lds(
        (const __attribute__((address_space(1))) void*)gsrc,
        (__attribute__((address_space(3))) void*)ldst,
        16, 0, 0);
}

// ---------------------------------------------------------------------------
// MFMA bf16 GEMM, NT: C[i][j] = scale * sum_k A[i,k]*B[j,k] (+bias[j])
// 128x128 tile, BK=32, 256 threads (4 waves, each 64x64 = 4x4 16x16 tiles).
// GRAM: A=B=X=[hi|mid|lo] (lda 3072); 6 chunk passes with COMPILE-TIME part
//       offsets (hi.hi, hi.mid, mid.hi, mid.mid, hi.lo, lo.hi == x.y to
//       ~fp32 accuracy); triangular grid (bi<=bj), 1/cdist epilogue +
//       mirrored store.
// OBF16: store output as bf16 (for q, kk feeding the aff MFMA).
// ---------------------------------------------------------------------------
template<bool GRAM, bool OBF16>
__global__ __launch_bounds__(256)
void mfma_gemm(const void* Av, long lda, long az,
               const void* Bv, long ldb, long bz,
               void* Cv, long ldc, long cz,
               int M, int N, int Kd,
               const float* __restrict__ bias, long biasz,
               float scale, const float* __restrict__ sqn, int nbm)
{
    __shared__ unsigned short As[128 * 32];
    __shared__ unsigned short Bs[128 * 32];
    const int t = threadIdx.x;
    const int w = t >> 6, l = t & 63;
    const int wr = w >> 1, wc = w & 1;

    int row0, col0, bi = 0, bj = 0;
    if (GRAM) {
        int tt = blockIdx.x, rem = nbm;
        while (tt >= rem) { tt -= rem; bi++; rem--; }
        bj = bi + tt;
        row0 = bi * 128; col0 = bj * 128;
    } else {
        row0 = blockIdx.y * 128; col0 = blockIdx.x * 128;
    }
    const int z = blockIdx.z;
    const unsigned short* Ab = (const unsigned short*)Av + (long)z * az;
    const unsigned short* Bb = (const unsigned short*)Bv + (long)z * bz;

    floatx4 acc[4][4];
#pragma unroll
    for (int i = 0; i < 4; i++)
#pragma unroll
        for (int j = 0; j < 4; j++) acc[i][j] = (floatx4){0.f, 0.f, 0.f, 0.f};

    // clamped staging row indices (hoisted out of the K loop)
    int ra0 = row0 + (w * 2 + 0) * 16 + (l >> 2); ra0 = ra0 < M ? ra0 : M - 1;
    int ra1 = row0 + (w * 2 + 1) * 16 + (l >> 2); ra1 = ra1 < M ? ra1 : M - 1;
    int rb0 = col0 + (w * 2 + 0) * 16 + (l >> 2); rb0 = rb0 < N ? rb0 : N - 1;
    int rb1 = col0 + (w * 2 + 1) * 16 + (l >> 2); rb1 = rb1 < N ? rb1 : N - 1;
    const long lane_off = (l & 3) * 8;
    const unsigned short* gA0 = Ab + (long)ra0 * lda + lane_off;
    const unsigned short* gA1 = Ab + (long)ra1 * lda + lane_off;
    const unsigned short* gB0 = Bb + (long)rb0 * ldb + lane_off;
    const unsigned short* gB1 = Bb + (long)rb1 * ldb + lane_off;
    unsigned short* lA0 = As + ((w * 2 + 0) * 16) * 32;
    unsigned short* lA1 = As + ((w * 2 + 1) * 16) * 32;
    unsigned short* lB0 = Bs + ((w * 2 + 0) * 16) * 32;
    unsigned short* lB1 = Bs + ((w * 2 + 1) * 16) * 32;

    auto kstep = [&](long offA, long offB) {
        async_copy16(gA0 + offA, (void*)lA0);
        async_copy16(gA1 + offA, (void*)lA1);
        async_copy16(gB0 + offB, (void*)lB0);
        async_copy16(gB1 + offB, (void*)lB1);
        __syncthreads();
        bf16x8 af[4], bfr[4];
#pragma unroll
        for (int ti = 0; ti < 4; ti++)
            af[ti] = *(const bf16x8*)(As + (wr * 64 + ti * 16 + (l & 15)) * 32 + (l >> 4) * 8);
#pragma unroll
        for (int tj = 0; tj < 4; tj++)
            bfr[tj] = *(const bf16x8*)(Bs + (wc * 64 + tj * 16 + (l & 15)) * 32 + (l >> 4) * 8);
#pragma unroll
        for (int ti = 0; ti < 4; ti++)
#pragma unroll
            for (int tj = 0; tj < 4; tj++)
                acc[ti][tj] = __builtin_amdgcn_mfma_f32_16x16x32_bf16(
                    af[ti], bfr[tj], acc[ti][tj], 0, 0, 0);
        __syncthreads();
    };

    if (GRAM) {
        // 6 chunk passes, compile-time part offsets (hi=0, mid=1024, lo=2048)
#pragma unroll 1
        for (int k0 = 0; k0 < 1024; k0 += 32) kstep(k0, k0);              // hi.hi
#pragma unroll 1
        for (int k0 = 0; k0 < 1024; k0 += 32) kstep(k0, k0 + 1024);      // hi.mid
#pragma unroll 1
        for (int k0 = 0; k0 < 1024; k0 += 32) kstep(k0 + 1024, k0);      // mid.hi
#pragma unroll 1
        for (int k0 = 0; k0 < 1024; k0 += 32) kstep(k0 + 1024, k0 + 1024); // mid.mid
#pragma unroll 1
        for (int k0 = 0; k0 < 1024; k0 += 32) kstep(k0, k0 + 2048);      // hi.lo
#pragma unroll 1
        for (int k0 = 0; k0 < 1024; k0 += 32) kstep(k0 + 2048, k0);      // lo.hi
    } else {
#pragma unroll 1
        for (int k0 = 0; k0 < Kd; k0 += 32) kstep(k0, k0);
    }

    float* Cf = (float*)Cv + (long)z * cz;
    unsigned short* Cb = (unsigned short*)Cv + (long)z * cz;
    const float* bias_p = bias ? bias + (long)z * biasz : nullptr;
#pragma unroll
    for (int ti = 0; ti < 4; ti++) {
#pragma unroll
        for (int tj = 0; tj < 4; tj++) {
            const int c = col0 + wc * 64 + tj * 16 + (l & 15);
            const int rb = row0 + wr * 64 + ti * 16 + (l >> 4) * 4;
            if (GRAM) {
                float rec4[4];
#pragma unroll
                for (int reg = 0; reg < 4; reg++) {
                    int r = rb + reg;
                    if (r >= M || c >= N) { rec4[reg] = 0.f; continue; }
                    if (r == c) { rec4[reg] = INFINITY; }
                    else {
                        float sq = sqn[r] + sqn[c] - 2.f * acc[ti][tj][reg];
                        rec4[reg] = 1.0f / sqrtf(fmaxf(sq, 0.f));
                    }
                    Cf[(long)r * ldc + c] = rec4[reg];
                }
                if (bi != bj && c < N && rb + 3 < M) {  // mirrored float4 store
                    *(float4*)(Cf + (long)c * ldc + rb) =
                        make_float4(rec4[0], rec4[1], rec4[2], rec4[3]);
                }
            } else {
#pragma unroll
                for (int reg = 0; reg < 4; reg++) {
                    int r = rb + reg;
                    if (r >= M || c >= N) continue;
                    float v = acc[ti][tj][reg] * scale;
                    if (bias_p) v += bias_p[c];
                    if (OBF16) Cb[(long)r * ldc + c] = f2bf(v);
                    else       Cf[(long)r * ldc + c] = v;
                }
            }
        }
    }
}

// ---------------------------------------------------------------------------
// fp32 SGEMM kept for the small Wv projection only.
// ---------------------------------------------------------------------------
#define BM 128
#define BN 128
#define BKK 8
#define TM 8
#define TN 8

template<bool TRANSB>
__global__ __launch_bounds__(256)
void sgemm_kernel(const float* __restrict__ A, long lda, long az,
                  const float* __restrict__ B, long ldb, long bz,
                  float* __restrict__ C, long ldc, long cz,
                  int M, int N, int Kd,
                  const float* __restrict__ bias, long biasz, float scale)
{
    __shared__ float As[BKK][BM];
    __shared__ float Bs[BKK][BN];
    const int t = threadIdx.x;
    const int z = blockIdx.z;
    A += (long)z * az; B += (long)z * bz; C += (long)z * cz;
    const float* bias_p = bias ? (bias + (long)z * biasz) : nullptr;
    const int row0 = blockIdx.y * BM;
    const int col0 = blockIdx.x * BN;
    const int tx = t & 15, ty = t >> 4;

    float acc[TM][TN];
#pragma unroll
    for (int i = 0; i < TM; i++)
#pragma unroll
        for (int j = 0; j < TN; j++) acc[i][j] = 0.f;

    const int lrow = t >> 1;
    const int lcol = (t & 1) * 4;

    for (int k0 = 0; k0 < Kd; k0 += BKK) {
        {
            int r = row0 + lrow; r = (r < M) ? r : (M - 1);
            float4 v = *(const float4*)(A + (long)r * lda + (k0 + lcol));
            As[lcol + 0][lrow] = v.x; As[lcol + 1][lrow] = v.y;
            As[lcol + 2][lrow] = v.z; As[lcol + 3][lrow] = v.w;
        }
        {
            int r = col0 + lrow; r = (r < N) ? r : (N - 1);
            float4 v = *(const float4*)(B + (long)r * ldb + (k0 + lcol));
            Bs[lcol + 0][lrow] = v.x; Bs[lcol + 1][lrow] = v.y;
            Bs[lcol + 2][lrow] = v.z; Bs[lcol + 3][lrow] = v.w;
        }
        __syncthreads();
#pragma unroll
        for (int kk = 0; kk < BKK; kk++) {
            float a[TM], b[TN];
#pragma unroll
            for (int i = 0; i < TM; i++) a[i] = As[kk][ty * TM + i];
#pragma unroll
            for (int j = 0; j < TN; j++) b[j] = Bs[kk][tx * TN + j];
#pragma unroll
            for (int i = 0; i < TM; i++)
#pragma unroll
                for (int j = 0; j < TN; j++)
                    acc[i][j] = fmaf(a[i], b[j], acc[i][j]);
        }
        __syncthreads();
    }
#pragma unroll
    for (int i = 0; i < TM; i++) {
        int r = row0 + ty * TM + i;
        if (r >= M) continue;
#pragma unroll
        for (int j = 0; j < TN; j++) {
            int c = col0 + tx * TN + j;
            if (c >= N) continue;
            float v = acc[i][j] * scale;
            if (bias_p) v += bias_p[c];
            C[(long)r * ldc + c] = v;
        }
    }
}

// ---------------------------------------------------------------------------
// Fused: sqn[r] = ||feat[r]||^2  AND  X = [hi|mid|lo] bf16 3-way split.
// One pass over feat (was two kernels reading it twice).
// ---------------------------------------------------------------------------
__global__ __launch_bounds__(256)
void sqnpack3_kernel(const float* __restrict__ feat,
                     unsigned short* __restrict__ X, float* __restrict__ sqn)
{
    const int r = blockIdx.x, t = threadIdx.x;
    float4 v = *(const float4*)(feat + (long)r * DIM + t * 4);
    float s = v.x * v.x + v.y * v.y + v.z * v.z + v.w * v.w;

    ushort4 hi, mid, lo;
    float rx, ry, rz, rw;
    hi.x = f2bf(v.x); rx = v.x - bf2f(hi.x);
    hi.y = f2bf(v.y); ry = v.y - bf2f(hi.y);
    hi.z = f2bf(v.z); rz = v.z - bf2f(hi.z);
    hi.w = f2bf(v.w); rw = v.w - bf2f(hi.w);
    mid.x = f2bf(rx); rx -= bf2f(mid.x);
    mid.y = f2bf(ry); ry -= bf2f(mid.y);
    mid.z = f2bf(rz); rz -= bf2f(mid.z);
    mid.w = f2bf(rw); rw -= bf2f(mid.w);
    lo.x = f2bf(rx); lo.y = f2bf(ry); lo.z = f2bf(rz); lo.w = f2bf(rw);
    *(ushort4*)(X + (long)r * XSTR + t * 4) = hi;
    *(ushort4*)(X + (long)r * XSTR + 1024 + t * 4) = mid;
    *(ushort4*)(X + (long)r * XSTR + 2048 + t * 4) = lo;

#pragma unroll
    for (int o = 32; o > 0; o >>= 1) s += __shfl_down(s, o);
    __shared__ float sr[4];
    if ((t & 63) == 0) sr[t >> 6] = s;
    __syncthreads();
    if (t == 0) sqn[r] = sr[0] + sr[1] + sr[2] + sr[3];
}

// Both weight conversions in one launch: blocks [0,1024) -> Wq, [1024,2048) -> Wk
__global__ __launch_bounds__(256)
void wconv2_kernel(const float* __restrict__ Wq, const float* __restrict__ Wk,
                   unsigned short* __restrict__ Wq_b, unsigned short* __restrict__ Wk_b)
{
    const int b = blockIdx.x;
    const float* src = (b < 1024) ? Wq : Wk;
    unsigned short* dst = (b < 1024) ? Wq_b : Wk_b;
    const long i = ((long)(b & 1023) * 256 + threadIdx.x) * 4;
    float4 v = *(const float4*)(src + i);
    ushort4 o;
    o.x = f2bf(v.x); o.y = f2bf(v.y); o.z = f2bf(v.z); o.w = f2bf(v.w);
    *(ushort4*)(dst + i) = o;
}

// featT[d][r] = bf16(feat[r][d]), 1024 x 6016 (cols 6000..6015 zero)
__global__ __launch_bounds__(256)
void transpose_kernel(const float* __restrict__ feat, unsigned short* __restrict__ featT)
{
    __shared__ unsigned short tile[32][33];
    const int bx = blockIdx.x;   // d-block 0..31
    const int by = blockIdx.y;   // r-block 0..187
    const int t = threadIdx.x;
    const int lr = t >> 3;
    const int lc = (t & 7) * 4;
    const int r = by * 32 + lr;
    if (r < N_PTS) {
        float4 v = *(const float4*)(feat + (long)r * DIM + bx * 32 + lc);
        tile[lr][lc + 0] = f2bf(v.x); tile[lr][lc + 1] = f2bf(v.y);
        tile[lr][lc + 2] = f2bf(v.z); tile[lr][lc + 3] = f2bf(v.w);
    } else {
        tile[lr][lc + 0] = 0; tile[lr][lc + 1] = 0;
        tile[lr][lc + 2] = 0; tile[lr][lc + 3] = 0;
    }
    __syncthreads();
    const int orow = bx * 32 + lr;
    ushort4 o;
    o.x = tile[lc + 0][lr]; o.y = tile[lc + 1][lr];
    o.z = tile[lc + 2][lr]; o.w = tile[lc + 3][lr];
    *(ushort4*)(featT + (long)orow * WSTR + by * 32 + lc) = o;
}

// ---------------------------------------------------------------------------
// Greedy FPS — R4 structure (measured 470 us; R5 restructure regressed, reverted).
// 1024 threads x 6 elements, two-stage shfl_down reduction, two barriers.
// ---------------------------------------------------------------------------
#define FPS_T 1024
#define FPS_E 6

__global__ __launch_bounds__(1024)
void fps_kernel(const float* __restrict__ Drec, int* __restrict__ idxout)
{
    const int t = threadIdx.x;
    float ds[FPS_E];
#pragma unroll
    for (int j = 0; j < FPS_E; j++) {
        int n = t + j * FPS_T;
        ds[j] = (n < N_PTS) ? Drec[n] : INFINITY;
    }
    __shared__ unsigned long long red[16];
    __shared__ int s_sel;
    if (t == 0) idxout[0] = 0;

    for (int it = 1; it < KSEL; it++) {
        float mv = ds[0]; int mi = t;
#pragma unroll
        for (int j = 1; j < FPS_E; j++) {
            int n = t + j * FPS_T;
            if (ds[j] < mv) { mv = ds[j]; mi = n; }
        }
        unsigned long long key =
            ((unsigned long long)__float_as_uint(mv) << 32) | (unsigned)mi;
#pragma unroll
        for (int o = 32; o > 0; o >>= 1) {
            unsigned long long other = __shfl_down(key, o);
            if (other < key) key = other;
        }
        if ((t & 63) == 0) red[t >> 6] = key;
        __syncthreads();
        if (t < 64) {
            unsigned long long k2 = (t < 16) ? red[t] : ~0ull;
#pragma unroll
            for (int o = 8; o > 0; o >>= 1) {
                unsigned long long other = __shfl_down(k2, o);
                if (other < k2) k2 = other;
            }
            if (t == 0) s_sel = (int)(unsigned)(k2 & 0xffffffffull);
        }
        __syncthreads();
        const int sel = s_sel;
        if (t == 0) idxout[it] = sel;
        const float* row = Drec + (long)sel * N_PTS;
#pragma unroll
        for (int j = 0; j < FPS_E; j++) {
            int n = t + j * FPS_T;
            if (n < N_PTS) ds[j] += row[n];
        }
    }
}

__global__ __launch_bounds__(256)
void gatherb_kernel(const unsigned short* __restrict__ X, const int* __restrict__ idx,
                    unsigned short* __restrict__ roi)
{
    const int k = blockIdx.x, t = threadIdx.x;
    const unsigned short* src = X + (long)idx[k] * XSTR;
    *(ushort4*)(roi + (long)k * DIM + t * 4) = *(const ushort4*)(src + t * 4);
}

// ---------------------------------------------------------------------------
// Fused gate + softmax: one block per (k,g) row of W (in-place fp32 -> bf16).
// ---------------------------------------------------------------------------
__global__ __launch_bounds__(256)
void gatesoftmax_kernel(const float* __restrict__ bboxes,
                        const int* __restrict__ idx,
                        const float* __restrict__ Wg,
                        const float* __restrict__ bgp,
                        float* __restrict__ W)
{
    __shared__ float lg[WSTR];      // 24 KB: logits, then exp values
    __shared__ float swg[64];
    __shared__ float sred[4];
    __shared__ float sbb[4];
    __shared__ float sMS;
    const int t = threadIdx.x;
    const int row = blockIdx.x;     // k*GG + g
    const int k = row >> 4, g = row & 15;
    float* rowp = W + (long)row * WSTR;

    if (t < 64) swg[t] = Wg[g * 64 + t];
    if (t < 4)  sbb[t] = bboxes[(long)idx[k] * 4 + t];
    __syncthreads();

    const float x1 = sbb[0], y1 = sbb[1], x2 = sbb[2], y2 = sbb[3];
    const float w  = x2 - x1 + 1.f, h = y2 - y1 + 1.f;
    const float cx = 0.5f * (x1 + x2), cy = 0.5f * (y1 + y2);
    const float bg_g = bgp[g];
    const float rdm[8] = { 100.0f, 42.169650342858226f, 17.782794100389228f,
                           7.498942093324559f, 3.1622776601683795f,
                           1.333521432163324f, 0.5623413251903491f,
                           0.23713737056616552f };

    float m = -INFINITY;
    for (int n = t; n < N_PTS; n += 256) {
        const float aff = rowp[n];
        float4 rb = *(const float4*)(bboxes + (long)n * 4);
        const float wr = rb.z - rb.x + 1.f, hr = rb.w - rb.y + 1.f;
        const float cxr = 0.5f * (rb.x + rb.z), cyr = 0.5f * (rb.y + rb.w);
        float pos[4];
        pos[0] = __logf(fabsf((cx - cxr) / w) + 1e-3f);
        pos[1] = __logf(fabsf((cy - cyr) / h) + 1e-3f);
        pos[2] = __logf(w / wr);
        pos[3] = __logf(h / hr);
        float gate = bg_g;
#pragma unroll
        for (int p = 0; p < 4; p++) {
#pragma unroll
            for (int f = 0; f < 8; f++) {
                const float arg = pos[p] * rdm[f];
                gate += swg[p * 16 + f] * __sinf(arg)
                      + swg[p * 16 + f + 8] * __cosf(arg);
            }
        }
        const float logit = aff + __logf(fmaxf(gate, 0.f) + 1e-6f);
        lg[n] = logit;
        m = fmaxf(m, logit);
    }
#pragma unroll
    for (int o = 32; o > 0; o >>= 1) m = fmaxf(m, __shfl_down(m, o));
    if ((t & 63) == 0) sred[t >> 6] = m;
    __syncthreads();
    if (t == 0) sMS = fmaxf(fmaxf(sred[0], sred[1]), fmaxf(sred[2], sred[3]));
    __syncthreads();
    m = sMS;
    __syncthreads();

    float s = 0.f;
    for (int n = t; n < N_PTS; n += 256) {
        const float e = __expf(lg[n] - m);
        lg[n] = e;
        s += e;
    }
#pragma unroll
    for (int o = 32; o > 0; o >>= 1) s += __shfl_down(s, o);
    if ((t & 63) == 0) sred[t >> 6] = s;
    __syncthreads();
    if (t == 0) sMS = sred[0] + sred[1] + sred[2] + sred[3];
    __syncthreads();
    const float inv = 1.0f / sMS;
    __syncthreads();

    unsigned short* orow = (unsigned short*)rowp;
    for (int n = t; n < WSTR; n += 256)
        orow[n] = (n < N_PTS) ? f2bf(lg[n] * inv) : (unsigned short)0;
}

// ---------------------------------------------------------------------------
extern "C" void kernel_launch(void* const* d_in, const int* in_sizes, int n_in,
                              void* d_out, int out_size, void* d_ws, size_t ws_size,
                              hipStream_t stream)
{
    const float* feat   = (const float*)d_in[0];
    const float* bboxes = (const float*)d_in[1];
    const float* Wq     = (const float*)d_in[2];
    const float* bq     = (const float*)d_in[3];
    const float* Wk     = (const float*)d_in[4];
    const float* bk     = (const float*)d_in[5];
    const float* Wg     = (const float*)d_in[6];
    const float* bg     = (const float*)d_in[7];
    const float* Wv     = (const float*)d_in[8];
    const float* bv     = (const float*)d_in[9];
    float* out = (float*)d_out;
    float* ws  = (float*)d_ws;

    // ws layout (float offsets), peak ~185.1 MB (same as R4/R5):
    //  [0 .. 36,000,000)  drec 6000x6000. Dead after FPS; then reused:
    //      W     [0, 28,876,800)            4800 x 6016 logits (fp32 -> bf16 in place)
    //      kk_b  [28,900,000, 31,972,000)   6000x1024 bf16
    //      q_b   [31,972,000, 32,125,600)   300x1024 bf16
    //      roi_b [32,125,600, 32,279,200)   300x1024 bf16
    //      featT [32,300,000, 35,380,192)   1024x6016 bf16 (written post-FPS)
    //  [36,000,000 .. 45,216,000)  X=[hi|mid|lo] 6000x3072 bf16
    //      -> outt fp32 4800x1024 reuses [36,000,000, 40,915,200) after kk/gather
    //  [45,216,000 .. 45,740,288)  Wq_b
    //  [45,740,288 .. 46,264,576)  Wk_b
    //  [46,264,576 .. 46,270,576)  sqn
    //  [46,270,576 .. )            idx (300 ints)
    float* drec = ws;
    float* W    = ws;
    unsigned short* kk_b  = (unsigned short*)(ws + 28900000);
    unsigned short* q_b   = (unsigned short*)(ws + 31972000);
    unsigned short* roi_b = (unsigned short*)(ws + 32125600);
    unsigned short* featT = (unsigned short*)(ws + 32300000);
    unsigned short* X     = (unsigned short*)(ws + 36000000);
    float* outt           = ws + 36000000;
    unsigned short* Wq_b  = (unsigned short*)(ws + 45216000);
    unsigned short* Wk_b  = (unsigned short*)(ws + 45740288);
    float* sqnbuf         = ws + 46264576;
    int*   idxbuf         = (int*)(ws + 46270576);
    if (ws_size < (size_t)185100000) return;

    sqnpack3_kernel<<<N_PTS, 256, 0, stream>>>(feat, X, sqnbuf);
    wconv2_kernel<<<2048, 256, 0, stream>>>(Wq, Wk, Wq_b, Wk_b);

    // Gram: 3-way split bf16, 6 chunk passes, triangular grid
    mfma_gemm<true, false><<<1128, 256, 0, stream>>>(
        X, XSTR, 0, X, XSTR, 0, drec, N_PTS, 0,
        N_PTS, N_PTS, 6144, nullptr, 0, 1.f, sqnbuf, 47);

    fps_kernel<<<1, FPS_T, 0, stream>>>(drec, idxbuf);

    // featT goes into dead drec space -> must run after FPS
    transpose_kernel<<<dim3(32, 188), 256, 0, stream>>>(feat, featT);
    gatherb_kernel<<<KSEL, 256, 0, stream>>>(X, idxbuf, roi_b);

    // q = roi @ Wq^T + bq  (bf16 out)
    mfma_gemm<false, true><<<dim3(8, 3, 1), 256, 0, stream>>>(
        roi_b, 1024, 0, Wq_b, 1024, 0, q_b, 1024, 0,
        KSEL, DIM, DIM, bq, 0, 1.f, nullptr, 0);
    // kk = feat @ Wk^T + bk  (bf16 out; A = hi part of X, lda XSTR)
    mfma_gemm<false, true><<<dim3(8, 47, 1), 256, 0, stream>>>(
        X, XSTR, 0, Wk_b, 1024, 0, kk_b, 1024, 0,
        N_PTS, DIM, DIM, bk, 0, 1.f, nullptr, 0);

    // aff = (q . kk^T)/8 per group -> W fp32  (batched z=16, K=64)
    mfma_gemm<false, false><<<dim3(47, 3, GG), 256, 0, stream>>>(
        q_b, 1024, 64, kk_b, 1024, 64, W, (long)GG * WSTR, WSTR,
        KSEL, N_PTS, 64, nullptr, 0, 0.125f, nullptr, 0);

    // fused gate + softmax; W rows become bf16 probs in place
    gatesoftmax_kernel<<<KSEL * GG, 256, 0, stream>>>(bboxes, idxbuf, Wg, bg, W);

    // out_t = P @ feat  (A = bf16 probs in place, lda 2*WSTR shorts; B = featT)
    mfma_gemm<false, false><<<dim3(8, 38, 1), 256, 0, stream>>>(
        (unsigned short*)W, 2 * WSTR, 0, featT, WSTR, 0, outt, DIM, 0,
        KSEL * GG, DIM, WSTR, nullptr, 0, 1.f, nullptr, 0);

    // out = out_t . Wv + bv (fp32, small)
    sgemm_kernel<true><<<dim3(1, 3, GG), 256, 0, stream>>>(
        outt, (long)GG * DIM, DIM, Wv, DIM, (long)DGR * DIM, out, DIM, DGR,
        KSEL, DGR, DIM, bv, DGR, 1.f);
}

// Round 7
// 1584.579 us; speedup vs baseline: 1.1613x; 1.0535x over previous
//
#include <hip/hip_runtime.h>
#include <math.h>

#define N_PTS 6000
#define DIM   1024
#define KSEL  300
#define GG    16
#define DGR   64
#define WSTR  6016   // padded row stride for logits W (6000 -> 6016)
#define XSTR  3072   // X = [hi|mid|lo] bf16 split, row stride

typedef short bf16x8 __attribute__((ext_vector_type(8)));
typedef float floatx4 __attribute__((ext_vector_type(4)));

__device__ __forceinline__ unsigned short f2bf(float x) {
    unsigned u = __float_as_uint(x);
    unsigned r = u + 0x7FFFu + ((u >> 16) & 1u);   // RNE
    return (unsigned short)(r >> 16);
}
__device__ __forceinline__ float bf2f(unsigned short h) {
    return __uint_as_float(((unsigned)h) << 16);
}

__device__ __forceinline__ void async_copy16(const void* gsrc, void* ldst) {
    __builtin_amdgcn_global_load_lds(
        (const __attribute__((address_space(1))) void*)gsrc,
        (__attribute__((address_space(3))) void*)ldst,
        16, 0, 0);
}

// ---------------------------------------------------------------------------
// MFMA bf16 GEMM, NT: C[i][j] = scale * sum_k A[i,k]*B[j,k] (+bias[j])
// 128x128 tile, BK=32, 256 threads (4 waves, each 64x64 = 4x4 16x16 tiles).
// GRAM: A=B=X=[hi|mid|lo] (lda 3072); 6 chunk passes with COMPILE-TIME part
//       offsets (hi.hi, hi.mid, mid.hi, mid.mid, hi.lo, lo.hi == x.y to
//       ~fp32 accuracy); triangular grid (bi<=bj), 1/cdist epilogue +
//       mirrored store.
// OBF16: store output as bf16 (for q, kk feeding the aff MFMA).
// ---------------------------------------------------------------------------
template<bool GRAM, bool OBF16>
__global__ __launch_bounds__(256)
void mfma_gemm(const void* Av, long lda, long az,
               const void* Bv, long ldb, long bz,
               void* Cv, long ldc, long cz,
               int M, int N, int Kd,
               const float* __restrict__ bias, long biasz,
               float scale, const float* __restrict__ sqn, int nbm)
{
    __shared__ unsigned short As[128 * 32];
    __shared__ unsigned short Bs[128 * 32];
    const int t = threadIdx.x;
    const int w = t >> 6, l = t & 63;
    const int wr = w >> 1, wc = w & 1;

    int row0, col0, bi = 0, bj = 0;
    if (GRAM) {
        int tt = blockIdx.x, rem = nbm;
        while (tt >= rem) { tt -= rem; bi++; rem--; }
        bj = bi + tt;
        row0 = bi * 128; col0 = bj * 128;
    } else {
        row0 = blockIdx.y * 128; col0 = blockIdx.x * 128;
    }
    const int z = blockIdx.z;
    const unsigned short* Ab = (const unsigned short*)Av + (long)z * az;
    const unsigned short* Bb = (const unsigned short*)Bv + (long)z * bz;

    floatx4 acc[4][4];
#pragma unroll
    for (int i = 0; i < 4; i++)
#pragma unroll
        for (int j = 0; j < 4; j++) acc[i][j] = (floatx4){0.f, 0.f, 0.f, 0.f};

    // clamped staging row indices (hoisted out of the K loop)
    int ra0 = row0 + (w * 2 + 0) * 16 + (l >> 2); ra0 = ra0 < M ? ra0 : M - 1;
    int ra1 = row0 + (w * 2 + 1) * 16 + (l >> 2); ra1 = ra1 < M ? ra1 : M - 1;
    int rb0 = col0 + (w * 2 + 0) * 16 + (l >> 2); rb0 = rb0 < N ? rb0 : N - 1;
    int rb1 = col0 + (w * 2 + 1) * 16 + (l >> 2); rb1 = rb1 < N ? rb1 : N - 1;
    const long lane_off = (l & 3) * 8;
    const unsigned short* gA0 = Ab + (long)ra0 * lda + lane_off;
    const unsigned short* gA1 = Ab + (long)ra1 * lda + lane_off;
    const unsigned short* gB0 = Bb + (long)rb0 * ldb + lane_off;
    const unsigned short* gB1 = Bb + (long)rb1 * ldb + lane_off;
    unsigned short* lA0 = As + ((w * 2 + 0) * 16) * 32;
    unsigned short* lA1 = As + ((w * 2 + 1) * 16) * 32;
    unsigned short* lB0 = Bs + ((w * 2 + 0) * 16) * 32;
    unsigned short* lB1 = Bs + ((w * 2 + 1) * 16) * 32;

    auto kstep = [&](long offA, long offB) {
        async_copy16(gA0 + offA, (void*)lA0);
        async_copy16(gA1 + offA, (void*)lA1);
        async_copy16(gB0 + offB, (void*)lB0);
        async_copy16(gB1 + offB, (void*)lB1);
        __syncthreads();
        bf16x8 af[4], bfr[4];
#pragma unroll
        for (int ti = 0; ti < 4; ti++)
            af[ti] = *(const bf16x8*)(As + (wr * 64 + ti * 16 + (l & 15)) * 32 + (l >> 4) * 8);
#pragma unroll
        for (int tj = 0; tj < 4; tj++)
            bfr[tj] = *(const bf16x8*)(Bs + (wc * 64 + tj * 16 + (l & 15)) * 32 + (l >> 4) * 8);
#pragma unroll
        for (int ti = 0; ti < 4; ti++)
#pragma unroll
            for (int tj = 0; tj < 4; tj++)
                acc[ti][tj] = __builtin_amdgcn_mfma_f32_16x16x32_bf16(
                    af[ti], bfr[tj], acc[ti][tj], 0, 0, 0);
        __syncthreads();
    };

    if (GRAM) {
        // 6 chunk passes, compile-time part offsets (hi=0, mid=1024, lo=2048)
#pragma unroll 1
        for (int k0 = 0; k0 < 1024; k0 += 32) kstep(k0, k0);              // hi.hi
#pragma unroll 1
        for (int k0 = 0; k0 < 1024; k0 += 32) kstep(k0, k0 + 1024);      // hi.mid
#pragma unroll 1
        for (int k0 = 0; k0 < 1024; k0 += 32) kstep(k0 + 1024, k0);      // mid.hi
#pragma unroll 1
        for (int k0 = 0; k0 < 1024; k0 += 32) kstep(k0 + 1024, k0 + 1024); // mid.mid
#pragma unroll 1
        for (int k0 = 0; k0 < 1024; k0 += 32) kstep(k0, k0 + 2048);      // hi.lo
#pragma unroll 1
        for (int k0 = 0; k0 < 1024; k0 += 32) kstep(k0 + 2048, k0);      // lo.hi
    } else {
#pragma unroll 1
        for (int k0 = 0; k0 < Kd; k0 += 32) kstep(k0, k0);
    }

    float* Cf = (float*)Cv + (long)z * cz;
    unsigned short* Cb = (unsigned short*)Cv + (long)z * cz;
    const float* bias_p = bias ? bias + (long)z * biasz : nullptr;
#pragma unroll
    for (int ti = 0; ti < 4; ti++) {
#pragma unroll
        for (int tj = 0; tj < 4; tj++) {
            const int c = col0 + wc * 64 + tj * 16 + (l & 15);
            const int rb = row0 + wr * 64 + ti * 16 + (l >> 4) * 4;
            if (GRAM) {
                float rec4[4];
#pragma unroll
                for (int reg = 0; reg < 4; reg++) {
                    int r = rb + reg;
                    if (r >= M || c >= N) { rec4[reg] = 0.f; continue; }
                    if (r == c) { rec4[reg] = INFINITY; }
                    else {
                        float sq = sqn[r] + sqn[c] - 2.f * acc[ti][tj][reg];
                        rec4[reg] = 1.0f / sqrtf(fmaxf(sq, 0.f));
                    }
                    Cf[(long)r * ldc + c] = rec4[reg];
                }
                if (bi != bj && c < N && rb + 3 < M) {  // mirrored float4 store
                    *(float4*)(Cf + (long)c * ldc + rb) =
                        make_float4(rec4[0], rec4[1], rec4[2], rec4[3]);
                }
            } else {
#pragma unroll
                for (int reg = 0; reg < 4; reg++) {
                    int r = rb + reg;
                    if (r >= M || c >= N) continue;
                    float v = acc[ti][tj][reg] * scale;
                    if (bias_p) v += bias_p[c];
                    if (OBF16) Cb[(long)r * ldc + c] = f2bf(v);
                    else       Cf[(long)r * ldc + c] = v;
                }
            }
        }
    }
}

// ---------------------------------------------------------------------------
// fp32 SGEMM kept for the small Wv projection only.
// ---------------------------------------------------------------------------
#define BM 128
#define BN 128
#define BKK 8
#define TM 8
#define TN 8

template<bool TRANSB>
__global__ __launch_bounds__(256)
void sgemm_kernel(const float* __restrict__ A, long lda, long az,
                  const float* __restrict__ B, long ldb, long bz,
                  float* __restrict__ C, long ldc, long cz,
                  int M, int N, int Kd,
                  const float* __restrict__ bias, long biasz, float scale)
{
    __shared__ float As[BKK][BM];
    __shared__ float Bs[BKK][BN];
    const int t = threadIdx.x;
    const int z = blockIdx.z;
    A += (long)z * az; B += (long)z * bz; C += (long)z * cz;
    const float* bias_p = bias ? (bias + (long)z * biasz) : nullptr;
    const int row0 = blockIdx.y * BM;
    const int col0 = blockIdx.x * BN;
    const int tx = t & 15, ty = t >> 4;

    float acc[TM][TN];
#pragma unroll
    for (int i = 0; i < TM; i++)
#pragma unroll
        for (int j = 0; j < TN; j++) acc[i][j] = 0.f;

    const int lrow = t >> 1;
    const int lcol = (t & 1) * 4;

    for (int k0 = 0; k0 < Kd; k0 += BKK) {
        {
            int r = row0 + lrow; r = (r < M) ? r : (M - 1);
            float4 v = *(const float4*)(A + (long)r * lda + (k0 + lcol));
            As[lcol + 0][lrow] = v.x; As[lcol + 1][lrow] = v.y;
            As[lcol + 2][lrow] = v.z; As[lcol + 3][lrow] = v.w;
        }
        {
            int r = col0 + lrow; r = (r < N) ? r : (N - 1);
            float4 v = *(const float4*)(B + (long)r * ldb + (k0 + lcol));
            Bs[lcol + 0][lrow] = v.x; Bs[lcol + 1][lrow] = v.y;
            Bs[lcol + 2][lrow] = v.z; Bs[lcol + 3][lrow] = v.w;
        }
        __syncthreads();
#pragma unroll
        for (int kk = 0; kk < BKK; kk++) {
            float a[TM], b[TN];
#pragma unroll
            for (int i = 0; i < TM; i++) a[i] = As[kk][ty * TM + i];
#pragma unroll
            for (int j = 0; j < TN; j++) b[j] = Bs[kk][tx * TN + j];
#pragma unroll
            for (int i = 0; i < TM; i++)
#pragma unroll
                for (int j = 0; j < TN; j++)
                    acc[i][j] = fmaf(a[i], b[j], acc[i][j]);
        }
        __syncthreads();
    }
#pragma unroll
    for (int i = 0; i < TM; i++) {
        int r = row0 + ty * TM + i;
        if (r >= M) continue;
#pragma unroll
        for (int j = 0; j < TN; j++) {
            int c = col0 + tx * TN + j;
            if (c >= N) continue;
            float v = acc[i][j] * scale;
            if (bias_p) v += bias_p[c];
            C[(long)r * ldc + c] = v;
        }
    }
}

// ---------------------------------------------------------------------------
// Fused: sqn[r] = ||feat[r]||^2  AND  X = [hi|mid|lo] bf16 3-way split.
// ---------------------------------------------------------------------------
__global__ __launch_bounds__(256)
void sqnpack3_kernel(const float* __restrict__ feat,
                     unsigned short* __restrict__ X, float* __restrict__ sqn)
{
    const int r = blockIdx.x, t = threadIdx.x;
    float4 v = *(const float4*)(feat + (long)r * DIM + t * 4);
    float s = v.x * v.x + v.y * v.y + v.z * v.z + v.w * v.w;

    ushort4 hi, mid, lo;
    float rx, ry, rz, rw;
    hi.x = f2bf(v.x); rx = v.x - bf2f(hi.x);
    hi.y = f2bf(v.y); ry = v.y - bf2f(hi.y);
    hi.z = f2bf(v.z); rz = v.z - bf2f(hi.z);
    hi.w = f2bf(v.w); rw = v.w - bf2f(hi.w);
    mid.x = f2bf(rx); rx -= bf2f(mid.x);
    mid.y = f2bf(ry); ry -= bf2f(mid.y);
    mid.z = f2bf(rz); rz -= bf2f(mid.z);
    mid.w = f2bf(rw); rw -= bf2f(mid.w);
    lo.x = f2bf(rx); lo.y = f2bf(ry); lo.z = f2bf(rz); lo.w = f2bf(rw);
    *(ushort4*)(X + (long)r * XSTR + t * 4) = hi;
    *(ushort4*)(X + (long)r * XSTR + 1024 + t * 4) = mid;
    *(ushort4*)(X + (long)r * XSTR + 2048 + t * 4) = lo;

#pragma unroll
    for (int o = 32; o > 0; o >>= 1) s += __shfl_down(s, o);
    __shared__ float sr[4];
    if ((t & 63) == 0) sr[t >> 6] = s;
    __syncthreads();
    if (t == 0) sqn[r] = sr[0] + sr[1] + sr[2] + sr[3];
}

// Both weight conversions in one launch: blocks [0,1024) -> Wq, [1024,2048) -> Wk
__global__ __launch_bounds__(256)
void wconv2_kernel(const float* __restrict__ Wq, const float* __restrict__ Wk,
                   unsigned short* __restrict__ Wq_b, unsigned short* __restrict__ Wk_b)
{
    const int b = blockIdx.x;
    const float* src = (b < 1024) ? Wq : Wk;
    unsigned short* dst = (b < 1024) ? Wq_b : Wk_b;
    const long i = ((long)(b & 1023) * 256 + threadIdx.x) * 4;
    float4 v = *(const float4*)(src + i);
    ushort4 o;
    o.x = f2bf(v.x); o.y = f2bf(v.y); o.z = f2bf(v.z); o.w = f2bf(v.w);
    *(ushort4*)(dst + i) = o;
}

// featT[d][r] = bf16(feat[r][d]), 1024 x 6016 (cols 6000..6015 zero)
__global__ __launch_bounds__(256)
void transpose_kernel(const float* __restrict__ feat, unsigned short* __restrict__ featT)
{
    __shared__ unsigned short tile[32][33];
    const int bx = blockIdx.x;   // d-block 0..31
    const int by = blockIdx.y;   // r-block 0..187
    const int t = threadIdx.x;
    const int lr = t >> 3;
    const int lc = (t & 7) * 4;
    const int r = by * 32 + lr;
    if (r < N_PTS) {
        float4 v = *(const float4*)(feat + (long)r * DIM + bx * 32 + lc);
        tile[lr][lc + 0] = f2bf(v.x); tile[lr][lc + 1] = f2bf(v.y);
        tile[lr][lc + 2] = f2bf(v.z); tile[lr][lc + 3] = f2bf(v.w);
    } else {
        tile[lr][lc + 0] = 0; tile[lr][lc + 1] = 0;
        tile[lr][lc + 2] = 0; tile[lr][lc + 3] = 0;
    }
    __syncthreads();
    const int orow = bx * 32 + lr;
    ushort4 o;
    o.x = tile[lc + 0][lr]; o.y = tile[lc + 1][lr];
    o.z = tile[lc + 2][lr]; o.w = tile[lc + 3][lr];
    *(ushort4*)(featT + (long)orow * WSTR + by * 32 + lc) = o;
}

// ---------------------------------------------------------------------------
// Greedy FPS — R4 reduction (measured-good), float4 load path.
// Thread t < 750 owns n in [8t, 8t+8): two aligned global_load_dwordx4 per
// row (row base = sel*24000 B, 16B-aligned), no bounds checks (750*8=6000).
// Reduction/tie-break identical to R4: u64 (valbits<<32|n) two-stage
// shfl_down; ascending local scan keeps lowest n on ties.
// ---------------------------------------------------------------------------
#define FPS_T 1024

__global__ __launch_bounds__(1024)
void fps_kernel(const float* __restrict__ Drec, int* __restrict__ idxout)
{
    const int t = threadIdx.x;
    const bool act = t < 750;
    float ds[8];
    if (act) {
        const float4* p = (const float4*)Drec + 2 * t;
        float4 a0 = p[0], a1 = p[1];
        ds[0] = a0.x; ds[1] = a0.y; ds[2] = a0.z; ds[3] = a0.w;
        ds[4] = a1.x; ds[5] = a1.y; ds[6] = a1.z; ds[7] = a1.w;
    } else {
#pragma unroll
        for (int j = 0; j < 8; j++) ds[j] = INFINITY;
    }
    __shared__ unsigned long long red[16];
    __shared__ int s_sel;
    if (t == 0) idxout[0] = 0;

    for (int it = 1; it < KSEL; it++) {
        // local argmin over n = 8t..8t+7 (ascending -> lowest n wins ties)
        float mv = ds[0]; int mi = 8 * t;
#pragma unroll
        for (int j = 1; j < 8; j++) {
            if (ds[j] < mv) { mv = ds[j]; mi = 8 * t + j; }
        }
        unsigned long long key = act
            ? (((unsigned long long)__float_as_uint(mv) << 32) | (unsigned)mi)
            : ~0ull;
#pragma unroll
        for (int o = 32; o > 0; o >>= 1) {
            unsigned long long other = __shfl_down(key, o);
            if (other < key) key = other;
        }
        if ((t & 63) == 0) red[t >> 6] = key;
        __syncthreads();
        if (t < 64) {
            unsigned long long k2 = (t < 16) ? red[t] : ~0ull;
#pragma unroll
            for (int o = 8; o > 0; o >>= 1) {
                unsigned long long other = __shfl_down(k2, o);
                if (other < k2) k2 = other;
            }
            if (t == 0) s_sel = (int)(unsigned)(k2 & 0xffffffffull);
        }
        __syncthreads();
        const int sel = s_sel;
        if (t == 0) idxout[it] = sel;
        if (act) {
            const float4* rp = (const float4*)(Drec + (long)sel * N_PTS) + 2 * t;
            float4 r0 = rp[0], r1 = rp[1];
            ds[0] += r0.x; ds[1] += r0.y; ds[2] += r0.z; ds[3] += r0.w;
            ds[4] += r1.x; ds[5] += r1.y; ds[6] += r1.z; ds[7] += r1.w;
        }
    }
}

__global__ __launch_bounds__(256)
void gatherb_kernel(const unsigned short* __restrict__ X, const int* __restrict__ idx,
                    unsigned short* __restrict__ roi)
{
    const int k = blockIdx.x, t = threadIdx.x;
    const unsigned short* src = X + (long)idx[k] * XSTR;
    *(ushort4*)(roi + (long)k * DIM + t * 4) = *(const ushort4*)(src + t * 4);
}

// ---------------------------------------------------------------------------
// Fused gate + softmax: one block per (k,g) row of W (in-place fp32 -> bf16).
// ---------------------------------------------------------------------------
__global__ __launch_bounds__(256)
void gatesoftmax_kernel(const float* __restrict__ bboxes,
                        const int* __restrict__ idx,
                        const float* __restrict__ Wg,
                        const float* __restrict__ bgp,
                        float* __restrict__ W)
{
    __shared__ float lg[WSTR];      // 24 KB: logits, then exp values
    __shared__ float swg[64];
    __shared__ float sred[4];
    __shared__ float sbb[4];
    __shared__ float sMS;
    const int t = threadIdx.x;
    const int row = blockIdx.x;     // k*GG + g
    const int k = row >> 4, g = row & 15;
    float* rowp = W + (long)row * WSTR;

    if (t < 64) swg[t] = Wg[g * 64 + t];
    if (t < 4)  sbb[t] = bboxes[(long)idx[k] * 4 + t];
    __syncthreads();

    const float x1 = sbb[0], y1 = sbb[1], x2 = sbb[2], y2 = sbb[3];
    const float w  = x2 - x1 + 1.f, h = y2 - y1 + 1.f;
    const float cx = 0.5f * (x1 + x2), cy = 0.5f * (y1 + y2);
    const float bg_g = bgp[g];
    const float rdm[8] = { 100.0f, 42.169650342858226f, 17.782794100389228f,
                           7.498942093324559f, 3.1622776601683795f,
                           1.333521432163324f, 0.5623413251903491f,
                           0.23713737056616552f };

    float m = -INFINITY;
    for (int n = t; n < N_PTS; n += 256) {
        const float aff = rowp[n];
        float4 rb = *(const float4*)(bboxes + (long)n * 4);
        const float wr = rb.z - rb.x + 1.f, hr = rb.w - rb.y + 1.f;
        const float cxr = 0.5f * (rb.x + rb.z), cyr = 0.5f * (rb.y + rb.w);
        float pos[4];
        pos[0] = __logf(fabsf((cx - cxr) / w) + 1e-3f);
        pos[1] = __logf(fabsf((cy - cyr) / h) + 1e-3f);
        pos[2] = __logf(w / wr);
        pos[3] = __logf(h / hr);
        float gate = bg_g;
#pragma unroll
        for (int p = 0; p < 4; p++) {
#pragma unroll
            for (int f = 0; f < 8; f++) {
                const float arg = pos[p] * rdm[f];
                gate += swg[p * 16 + f] * __sinf(arg)
                      + swg[p * 16 + f + 8] * __cosf(arg);
            }
        }
        const float logit = aff + __logf(fmaxf(gate, 0.f) + 1e-6f);
        lg[n] = logit;
        m = fmaxf(m, logit);
    }
#pragma unroll
    for (int o = 32; o > 0; o >>= 1) m = fmaxf(m, __shfl_down(m, o));
    if ((t & 63) == 0) sred[t >> 6] = m;
    __syncthreads();
    if (t == 0) sMS = fmaxf(fmaxf(sred[0], sred[1]), fmaxf(sred[2], sred[3]));
    __syncthreads();
    m = sMS;
    __syncthreads();

    float s = 0.f;
    for (int n = t; n < N_PTS; n += 256) {
        const float e = __expf(lg[n] - m);
        lg[n] = e;
        s += e;
    }
#pragma unroll
    for (int o = 32; o > 0; o >>= 1) s += __shfl_down(s, o);
    if ((t & 63) == 0) sred[t >> 6] = s;
    __syncthreads();
    if (t == 0) sMS = sred[0] + sred[1] + sred[2] + sred[3];
    __syncthreads();
    const float inv = 1.0f / sMS;
    __syncthreads();

    unsigned short* orow = (unsigned short*)rowp;
    for (int n = t; n < WSTR; n += 256)
        orow[n] = (n < N_PTS) ? f2bf(lg[n] * inv) : (unsigned short)0;
}

// ---------------------------------------------------------------------------
extern "C" void kernel_launch(void* const* d_in, const int* in_sizes, int n_in,
                              void* d_out, int out_size, void* d_ws, size_t ws_size,
                              hipStream_t stream)
{
    const float* feat   = (const float*)d_in[0];
    const float* bboxes = (const float*)d_in[1];
    const float* Wq     = (const float*)d_in[2];
    const float* bq     = (const float*)d_in[3];
    const float* Wk     = (const float*)d_in[4];
    const float* bk     = (const float*)d_in[5];
    const float* Wg     = (const float*)d_in[6];
    const float* bg     = (const float*)d_in[7];
    const float* Wv     = (const float*)d_in[8];
    const float* bv     = (const float*)d_in[9];
    float* out = (float*)d_out;
    float* ws  = (float*)d_ws;

    // ws layout (float offsets), peak ~185.1 MB (same as R6):
    //  [0 .. 36,000,000)  drec 6000x6000. Dead after FPS; then reused:
    //      W     [0, 28,876,800)            4800 x 6016 logits (fp32 -> bf16 in place)
    //      kk_b  [28,900,000, 31,972,000)   6000x1024 bf16
    //      q_b   [31,972,000, 32,125,600)   300x1024 bf16
    //      roi_b [32,125,600, 32,279,200)   300x1024 bf16
    //      featT [32,300,000, 35,380,192)   1024x6016 bf16 (written post-FPS)
    //  [36,000,000 .. 45,216,000)  X=[hi|mid|lo] 6000x3072 bf16
    //      -> outt fp32 4800x1024 reuses [36,000,000, 40,915,200) after kk/gather
    //  [45,216,000 .. 45,740,288)  Wq_b
    //  [45,740,288 .. 46,264,576)  Wk_b
    //  [46,264,576 .. 46,270,576)  sqn
    //  [46,270,576 .. )            idx (300 ints)
    float* drec = ws;
    float* W    = ws;
    unsigned short* kk_b  = (unsigned short*)(ws + 28900000);
    unsigned short* q_b   = (unsigned short*)(ws + 31972000);
    unsigned short* roi_b = (unsigned short*)(ws + 32125600);
    unsigned short* featT = (unsigned short*)(ws + 32300000);
    unsigned short* X     = (unsigned short*)(ws + 36000000);
    float* outt           = ws + 36000000;
    unsigned short* Wq_b  = (unsigned short*)(ws + 45216000);
    unsigned short* Wk_b  = (unsigned short*)(ws + 45740288);
    float* sqnbuf         = ws + 46264576;
    int*   idxbuf         = (int*)(ws + 46270576);
    if (ws_size < (size_t)185100000) return;

    sqnpack3_kernel<<<N_PTS, 256, 0, stream>>>(feat, X, sqnbuf);
    wconv2_kernel<<<2048, 256, 0, stream>>>(Wq, Wk, Wq_b, Wk_b);

    // Gram: 3-way split bf16, 6 chunk passes, triangular grid
    mfma_gemm<true, false><<<1128, 256, 0, stream>>>(
        X, XSTR, 0, X, XSTR, 0, drec, N_PTS, 0,
        N_PTS, N_PTS, 6144, nullptr, 0, 1.f, sqnbuf, 47);

    fps_kernel<<<1, FPS_T, 0, stream>>>(drec, idxbuf);

    // featT goes into dead drec space -> must run after FPS
    transpose_kernel<<<dim3(32, 188), 256, 0, stream>>>(feat, featT);
    gatherb_kernel<<<KSEL, 256, 0, stream>>>(X, idxbuf, roi_b);

    // q = roi @ Wq^T + bq  (bf16 out)
    mfma_gemm<false, true><<<dim3(8, 3, 1), 256, 0, stream>>>(
        roi_b, 1024, 0, Wq_b, 1024, 0, q_b, 1024, 0,
        KSEL, DIM, DIM, bq, 0, 1.f, nullptr, 0);
    // kk = feat @ Wk^T + bk  (bf16 out; A = hi part of X, lda XSTR)
    mfma_gemm<false, true><<<dim3(8, 47, 1), 256, 0, stream>>>(
        X, XSTR, 0, Wk_b, 1024, 0, kk_b, 1024, 0,
        N_PTS, DIM, DIM, bk, 0, 1.f, nullptr, 0);

    // aff = (q . kk^T)/8 per group -> W fp32  (batched z=16, K=64)
    mfma_gemm<false, false><<<dim3(47, 3, GG), 256, 0, stream>>>(
        q_b, 1024, 64, kk_b, 1024, 64, W, (long)GG * WSTR, WSTR,
        KSEL, N_PTS, 64, nullptr, 0, 0.125f, nullptr, 0);

    // fused gate + softmax; W rows become bf16 probs in place
    gatesoftmax_kernel<<<KSEL * GG, 256, 0, stream>>>(bboxes, idxbuf, Wg, bg, W);

    // out_t = P @ feat  (A = bf16 probs in place, lda 2*WSTR shorts; B = featT)
    mfma_gemm<false, false><<<dim3(8, 38, 1), 256, 0, stream>>>(
        (unsigned short*)W, 2 * WSTR, 0, featT, WSTR, 0, outt, DIM, 0,
        KSEL * GG, DIM, WSTR, nullptr, 0, 1.f, nullptr, 0);

    // out = out_t . Wv + bv (fp32, small)
    sgemm_kernel<true><<<dim3(1, 3, GG), 256, 0, stream>>>(
        outt, (long)GG * DIM, DIM, Wv, DIM, (long)DGR * DIM, out, DIM, DGR,
        KSEL, DGR, DIM, bv, DGR, 1.f);
}